// Round 4
// baseline (239.562 us; speedup 1.0000x reference)
//
#include <hip/hip_runtime.h>

// stimuli [4,32,304,608,1] fp32, eye [4,32,2,3] fp32
#define BH 304
#define BW 608
#define BHW (BH * BW)            // 184832
#define NFRAMES 128
#define GPR 152                  // groups (of 4 px) per row = 608/4
#define GPF (BH * GPR)           // groups per frame = 46208 = 361 * 128

typedef float vfloat4 __attribute__((ext_vector_type(4)));

__global__ __launch_bounds__(128) void warp_bilinear4_kernel(
    const float* __restrict__ stimuli,
    const float* __restrict__ eye,
    float* __restrict__ out)
{
    const int n = blockIdx.y;                      // frame (wave-uniform)
    const int g = blockIdx.x * 128 + threadIdx.x;  // group of 4 consecutive x pixels

    const int py  = g / GPR;
    const int px0 = (g - py * GPR) * 4;

    // Affine coefficients: wave-uniform -> scalar loads
    const float* aff = eye + n * 6;
    const float a00 = aff[0], a01 = aff[1], a02 = aff[2];
    const float a10 = aff[3], a11 = aff[4], a12 = aff[5];

    const float yy = -1.0f + 2.0f * (float)py / (float)(BH - 1);
    const float cy0 = a01 * yy + a02;   // x-transform const part
    const float cy1 = a11 * yy + a12;   // y-transform const part

    const float* __restrict__ img = stimuli + (size_t)n * BHW;

    int   idxA[4], idxB[4], idxC[4], idxD[4];
    float wa[4], wb[4], wc[4], wd[4];

    #pragma unroll
    for (int i = 0; i < 4; ++i) {
        const int px = px0 + i;
        const float xx = -1.0f + 2.0f * (float)px / (float)(BW - 1);
        const float x = (a00 * xx + cy0 + 1.0f) * (0.5f * (float)BW);
        const float y = (a10 * xx + cy1 + 1.0f) * (0.5f * (float)BH);

        int x0 = (int)floorf(x);
        int y0 = (int)floorf(y);
        int x1 = x0 + 1;
        int y1 = y0 + 1;
        x0 = min(max(x0, 0), BW - 1);
        x1 = min(max(x1, 0), BW - 1);
        y0 = min(max(y0, 0), BH - 1);
        y1 = min(max(y1, 0), BH - 1);

        idxA[i] = y0 * BW + x0;
        idxB[i] = y1 * BW + x0;
        idxC[i] = y0 * BW + x1;
        idxD[i] = y1 * BW + x1;

        const float x0f = (float)x0, x1f = (float)x1;
        const float y0f = (float)y0, y1f = (float)y1;
        wa[i] = (x1f - x) * (y1f - y);
        wb[i] = (x1f - x) * (y - y0f);
        wc[i] = (x - x0f) * (y1f - y);
        wd[i] = (x - x0f) * (y - y0f);
    }

    // 16 independent gathers in flight before a single waitcnt
    float Ia[4], Ib[4], Ic[4], Id[4];
    #pragma unroll
    for (int i = 0; i < 4; ++i) Ia[i] = img[idxA[i]];
    #pragma unroll
    for (int i = 0; i < 4; ++i) Ib[i] = img[idxB[i]];
    #pragma unroll
    for (int i = 0; i < 4; ++i) Ic[i] = img[idxC[i]];
    #pragma unroll
    for (int i = 0; i < 4; ++i) Id[i] = img[idxD[i]];

    vfloat4 r;
    r.x = wa[0]*Ia[0] + wb[0]*Ib[0] + wc[0]*Ic[0] + wd[0]*Id[0];
    r.y = wa[1]*Ia[1] + wb[1]*Ib[1] + wc[1]*Ic[1] + wd[1]*Id[1];
    r.z = wa[2]*Ia[2] + wb[2]*Ib[2] + wc[2]*Ic[2] + wd[2]*Id[2];
    r.w = wa[3]*Ia[3] + wb[3]*Ib[3] + wc[3]*Ic[3] + wd[3]*Id[3];

    vfloat4* dst = (vfloat4*)(out + (size_t)n * BHW + py * BW + px0);
    __builtin_nontemporal_store(r, dst);
}

extern "C" void kernel_launch(void* const* d_in, const int* in_sizes, int n_in,
                              void* d_out, int out_size, void* d_ws, size_t ws_size,
                              hipStream_t stream) {
    const float* stimuli = (const float*)d_in[0];
    const float* eye     = (const float*)d_in[1];
    float* out = (float*)d_out;

    dim3 grid(GPF / 128, NFRAMES);   // 361 x 128
    dim3 block(128);
    warp_bilinear4_kernel<<<grid, block, 0, stream>>>(stimuli, eye, out);
}

// Round 5
// 198.014 us; speedup vs baseline: 1.2098x; 1.2098x over previous
//
#include <hip/hip_runtime.h>

// stimuli [4,32,304,608,1] fp32, eye [4,32,2,3] fp32
#define BH 304
#define BW 608
#define BHW (BH * BW)     // 184832 = 512 * 361
#define NFRAMES 128

typedef float vf2 __attribute__((ext_vector_type(2)));

__global__ __launch_bounds__(256) void warp_bilinear2_kernel(
    const float* __restrict__ stimuli,
    const float* __restrict__ eye,
    float* __restrict__ out)
{
    const int n    = blockIdx.y;                       // frame (wave-uniform)
    const int base = blockIdx.x * 512 + threadIdx.x;   // 2 px/thread, wave-strided

    // Affine coefficients: wave-uniform -> scalar loads
    const float* aff = eye + n * 6;
    const float a00 = aff[0], a01 = aff[1], a02 = aff[2];
    const float a10 = aff[3], a11 = aff[4], a12 = aff[5];

    const float* __restrict__ img = stimuli + (size_t)n * BHW;

    float xs[2], ys[2];
    int   x0s[2], y0s[2];
    vf2   vA[2], vB[2];   // row-y0 pair, row-y1 pair

    // Phase 1: coords + issue all 4 dwordx2 gathers
    #pragma unroll
    for (int k = 0; k < 2; ++k) {
        const int p  = base + k * 256;
        const int py = p / BW;
        const int px = p - py * BW;

        const float xx = -1.0f + 2.0f * (float)px / (float)(BW - 1);
        const float yy = -1.0f + 2.0f * (float)py / (float)(BH - 1);
        const float x = (a00 * xx + a01 * yy + a02 + 1.0f) * (0.5f * (float)BW);
        const float y = (a10 * xx + a11 * yy + a12 + 1.0f) * (0.5f * (float)BH);
        xs[k] = x; ys[k] = y;

        const int x0 = (int)floorf(x);
        const int y0 = (int)floorf(y);
        x0s[k] = x0; y0s[k] = y0;

        const int xp  = min(max(x0, 0), BW - 2);       // pair base: [xp, xp+1] in-bounds
        const int y0c = min(max(y0,     0), BH - 1);
        const int y1c = min(max(y0 + 1, 0), BH - 1);

        __builtin_memcpy(&vA[k], img + y0c * BW + xp, 8);
        __builtin_memcpy(&vB[k], img + y1c * BW + xp, 8);
    }

    // Phase 2: select taps, blend, store
    #pragma unroll
    for (int k = 0; k < 2; ++k) {
        const float x = xs[k], y = ys[k];
        const int x0 = x0s[k], y0 = y0s[k];

        const int xp  = min(max(x0, 0), BW - 2);
        const int x0c = min(max(x0,     0), BW - 1);
        const int x1c = min(max(x0 + 1, 0), BW - 1);
        const int y0c = min(max(y0,     0), BH - 1);
        const int y1c = min(max(y0 + 1, 0), BH - 1);

        // x0c > xp only when clamped to W-1 (xp = W-2); x1c > xp in the normal case too
        const float Ia = (x0c > xp) ? vA[k].y : vA[k].x;
        const float Ic = (x1c > xp) ? vA[k].y : vA[k].x;
        const float Ib = (x0c > xp) ? vB[k].y : vB[k].x;
        const float Id = (x1c > xp) ? vB[k].y : vB[k].x;

        const float x0f = (float)x0c, x1f = (float)x1c;
        const float y0f = (float)y0c, y1f = (float)y1c;
        const float wa = (x1f - x) * (y1f - y);
        const float wb = (x1f - x) * (y - y0f);
        const float wc = (x - x0f) * (y1f - y);
        const float wd = (x - x0f) * (y - y0f);

        out[(size_t)n * BHW + base + k * 256] = wa * Ia + wb * Ib + wc * Ic + wd * Id;
    }
}

extern "C" void kernel_launch(void* const* d_in, const int* in_sizes, int n_in,
                              void* d_out, int out_size, void* d_ws, size_t ws_size,
                              hipStream_t stream) {
    const float* stimuli = (const float*)d_in[0];
    const float* eye     = (const float*)d_in[1];
    float* out = (float*)d_out;

    dim3 grid(BHW / 512, NFRAMES);   // 361 x 128
    dim3 block(256);
    warp_bilinear2_kernel<<<grid, block, 0, stream>>>(stimuli, eye, out);
}

// Round 6
// 194.211 us; speedup vs baseline: 1.2335x; 1.0196x over previous
//
#include <hip/hip_runtime.h>

// stimuli [4,32,304,608,1] fp32, eye [4,32,2,3] fp32
#define BH 304
#define BW 608
#define BHW (BH * BW)     // 184832 = 512 * 361
#define NFRAMES 128

typedef float vf2 __attribute__((ext_vector_type(2)));

// 128 threads/block, 4 px/thread at stride 128 -> block covers 512 consecutive px.
// Each wave-gather's 64 lanes cover 64 consecutive output pixels (max line sharing).
__global__ __launch_bounds__(128) void warp_bilinear4s_kernel(
    const float* __restrict__ stimuli,
    const float* __restrict__ eye,
    float* __restrict__ out)
{
    const int n     = blockIdx.y;                      // frame (wave-uniform)
    const int base  = blockIdx.x * 512 + threadIdx.x;  // first of 4 px, stride 128

    // Affine coefficients: wave-uniform -> scalar loads
    const float* aff = eye + n * 6;
    const float a00 = aff[0], a01 = aff[1], a02 = aff[2];
    const float a10 = aff[3], a11 = aff[4], a12 = aff[5];

    const float* __restrict__ img = stimuli + (size_t)n * BHW;

    float xs[4], ys[4];
    int   x0s[4], y0s[4];
    vf2   vA[4], vB[4];   // row-y0 pair, row-y1 pair

    // Phase 1: coords + issue all 8 dwordx2 gathers before any use
    #pragma unroll
    for (int k = 0; k < 4; ++k) {
        const int p  = base + k * 128;
        const int py = p / BW;
        const int px = p - py * BW;

        const float xx = -1.0f + 2.0f * (float)px / (float)(BW - 1);
        const float yy = -1.0f + 2.0f * (float)py / (float)(BH - 1);
        const float x = (a00 * xx + a01 * yy + a02 + 1.0f) * (0.5f * (float)BW);
        const float y = (a10 * xx + a11 * yy + a12 + 1.0f) * (0.5f * (float)BH);
        xs[k] = x; ys[k] = y;

        const int x0 = (int)floorf(x);
        const int y0 = (int)floorf(y);
        x0s[k] = x0; y0s[k] = y0;

        const int xp  = min(max(x0, 0), BW - 2);       // pair base: [xp, xp+1] in-bounds
        const int y0c = min(max(y0,     0), BH - 1);
        const int y1c = min(max(y0 + 1, 0), BH - 1);

        const float* rowA = img + y0c * BW + xp;
        __builtin_memcpy(&vA[k], rowA, 8);
        __builtin_memcpy(&vB[k], rowA + (y1c - y0c) * BW, 8);
    }

    // Phase 2: select taps, blend, store (coalesced dword per k)
    #pragma unroll
    for (int k = 0; k < 4; ++k) {
        const float x = xs[k], y = ys[k];
        const int x0 = x0s[k], y0 = y0s[k];

        const int xp  = min(max(x0, 0), BW - 2);
        const int x0c = min(max(x0,     0), BW - 1);
        const int x1c = min(max(x0 + 1, 0), BW - 1);
        const int y0c = min(max(y0,     0), BH - 1);
        const int y1c = min(max(y0 + 1, 0), BH - 1);

        const float Ia = (x0c > xp) ? vA[k].y : vA[k].x;
        const float Ic = (x1c > xp) ? vA[k].y : vA[k].x;
        const float Ib = (x0c > xp) ? vB[k].y : vB[k].x;
        const float Id = (x1c > xp) ? vB[k].y : vB[k].x;

        const float x0f = (float)x0c, x1f = (float)x1c;
        const float y0f = (float)y0c, y1f = (float)y1c;
        const float wa = (x1f - x) * (y1f - y);
        const float wb = (x1f - x) * (y - y0f);
        const float wc = (x - x0f) * (y1f - y);
        const float wd = (x - x0f) * (y - y0f);

        out[(size_t)n * BHW + base + k * 128] = wa * Ia + wb * Ib + wc * Ic + wd * Id;
    }
}

extern "C" void kernel_launch(void* const* d_in, const int* in_sizes, int n_in,
                              void* d_out, int out_size, void* d_ws, size_t ws_size,
                              hipStream_t stream) {
    const float* stimuli = (const float*)d_in[0];
    const float* eye     = (const float*)d_in[1];
    float* out = (float*)d_out;

    dim3 grid(BHW / 512, NFRAMES);   // 361 x 128
    dim3 block(128);
    warp_bilinear4s_kernel<<<grid, block, 0, stream>>>(stimuli, eye, out);
}

// Round 7
// 192.287 us; speedup vs baseline: 1.2459x; 1.0100x over previous
//
#include <hip/hip_runtime.h>

// stimuli [4,32,304,608,1] fp32, eye [4,32,2,3] fp32
#define BH 304
#define BW 608
#define BHW (BH * BW)     // 184832 = 512 * 361
#define NFRAMES 128

typedef float vf2 __attribute__((ext_vector_type(2)));

// 128 threads/block, 4 px/thread at stride 128 -> block covers 512 consecutive px
// (spans at most 2 image rows -> y-side terms have only 2 candidates, hoisted).
// Outside x in [0,607) x y in [0,303) the reference's clamped-weight algebra
// cancels to exactly 0, so: bounds-mask + lerp instead of clamp/select taps.
__global__ __launch_bounds__(128) void warp_bilinear_lean_kernel(
    const float* __restrict__ stimuli,
    const float* __restrict__ eye,
    float* __restrict__ out)
{
    const int n    = blockIdx.y;            // frame (wave-uniform)
    const int blk  = blockIdx.x;
    const int base = blk * 512;             // block's first pixel (uniform)
    const int py0  = base / BW;             // uniform -> SALU
    const int pc0  = base - py0 * BW;       // column of first pixel (uniform)

    // Affine coefficients: wave-uniform -> scalar loads
    const float* aff = eye + n * 6;
    const float a00 = aff[0], a01 = aff[1], a02 = aff[2];
    const float a10 = aff[3], a11 = aff[4], a12 = aff[5];

    // Two candidate rows for this block; formula textually identical to prior rounds.
    const float yyr0 = -1.0f + 2.0f * (float)py0       / (float)(BH - 1);
    const float yyr1 = -1.0f + 2.0f * (float)(py0 + 1) / (float)(BH - 1);
    const float a01yy0 = a01 * yyr0, a01yy1 = a01 * yyr1;
    const float a11yy0 = a11 * yyr0, a11yy1 = a11 * yyr1;

    const float* __restrict__ img = stimuli + (size_t)n * BHW;

    float fxs[4], fys[4];
    bool  ok[4];
    vf2   vA[4], vB[4];

    // Phase 1: coords + issue all 8 dwordx2 gathers (row pair shares one address,
    // second row folds into a constant +BW*4 byte instruction offset).
    #pragma unroll
    for (int k = 0; k < 4; ++k) {
        const int off  = pc0 + (int)threadIdx.x + k * 128;   // < 2*BW
        const bool wrap = (off >= BW);
        const int px   = wrap ? off - BW : off;
        const float a01yy = wrap ? a01yy1 : a01yy0;
        const float a11yy = wrap ? a11yy1 : a11yy0;

        const float xx = -1.0f + 2.0f * (float)px / (float)(BW - 1);
        const float x = (a00 * xx + a01yy + a02 + 1.0f) * (0.5f * (float)BW);
        const float y = (a10 * xx + a11yy + a12 + 1.0f) * (0.5f * (float)BH);

        const float x0f = floorf(x);
        const float y0f = floorf(y);
        const int x0 = (int)x0f;
        const int y0 = (int)y0f;

        fxs[k] = x - x0f;                    // exact; == x - (float)x0c interior
        fys[k] = y - y0f;
        ok[k] = ((unsigned)x0 < (unsigned)(BW - 1)) & ((unsigned)y0 < (unsigned)(BH - 1));

        const int xp = min(max(x0, 0), BW - 2);   // address-safe pair base
        const int yp = min(max(y0, 0), BH - 2);
        const float* rowA = img + yp * BW + xp;
        __builtin_memcpy(&vA[k], rowA, 8);        // row y0: [x0, x0+1]
        __builtin_memcpy(&vB[k], rowA + BW, 8);   // row y0+1, same reg + imm offset
    }

    // Phase 2: factored bilinear lerp + zero-mask, coalesced stores
    #pragma unroll
    for (int k = 0; k < 4; ++k) {
        const float fx = fxs[k], fy = fys[k];
        const float ix0 = vA[k].x + fx * (vA[k].y - vA[k].x);
        const float ix1 = vB[k].x + fx * (vB[k].y - vB[k].x);
        float r = ix0 + fy * (ix1 - ix0);
        r = ok[k] ? r : 0.0f;
        out[(size_t)n * BHW + base + (int)threadIdx.x + k * 128] = r;
    }
}

extern "C" void kernel_launch(void* const* d_in, const int* in_sizes, int n_in,
                              void* d_out, int out_size, void* d_ws, size_t ws_size,
                              hipStream_t stream) {
    const float* stimuli = (const float*)d_in[0];
    const float* eye     = (const float*)d_in[1];
    float* out = (float*)d_out;

    dim3 grid(BHW / 512, NFRAMES);   // 361 x 128
    dim3 block(128);
    warp_bilinear_lean_kernel<<<grid, block, 0, stream>>>(stimuli, eye, out);
}